// Round 1
// baseline (548.836 us; speedup 1.0000x reference)
//
#include <hip/hip_runtime.h>
#include <stdint.h>

typedef unsigned short u16;
typedef __attribute__((ext_vector_type(8))) __bf16 bf16x8;
typedef __attribute__((ext_vector_type(4))) float f32x4;

#define BM 128
#define BN 128
#define BK 32

// bf16 bit patterns: +1 = 0x3F80, -1 = 0xBF80, 0 = 0x0000 (match jnp.sign)
__device__ __forceinline__ u16 sign_bf16(float v) {
  return v > 0.f ? (u16)0x3F80 : (v < 0.f ? (u16)0xBF80 : (u16)0);
}

// ---------------- quantize x: fp32 -> bf16 sign, 4 elems/thread ----------------
__global__ void quant_x_kernel(const float4* __restrict__ x, ushort4* __restrict__ xq, int n4) {
  int i = blockIdx.x * 256 + threadIdx.x;
  if (i >= n4) return;
  float4 v = x[i];
  ushort4 s;
  s.x = sign_bf16(v.x);
  s.y = sign_bf16(v.y);
  s.z = sign_bf16(v.z);
  s.w = sign_bf16(v.w);
  xq[i] = s;
}

// ------------- quantize w: one block per row; signs + mean(|w|) scale -------------
__global__ void quant_w_kernel(const float* __restrict__ w, u16* __restrict__ wq,
                               float* __restrict__ scale, int K) {
  const int row = blockIdx.x;
  const int t = threadIdx.x;
  const float* wr = w + (size_t)row * K;
  u16* wqr = wq + (size_t)row * K;
  float asum = 0.f;
  for (int p = 0; p < K; p += 1024) {  // 256 threads * float4 per pass
    int idx = p + t * 4;
    float4 v = *(const float4*)(wr + idx);
    ushort4 s;
    s.x = sign_bf16(v.x);
    s.y = sign_bf16(v.y);
    s.z = sign_bf16(v.z);
    s.w = sign_bf16(v.w);
    *(ushort4*)(wqr + idx) = s;
    asum += fabsf(v.x) + fabsf(v.y) + fabsf(v.z) + fabsf(v.w);
  }
  __shared__ float red[256];
  red[t] = asum;
  __syncthreads();
  for (int s2 = 128; s2 > 0; s2 >>= 1) {
    if (t < s2) red[t] += red[t + s2];
    __syncthreads();
  }
  if (t == 0) scale[row] = red[0] / (float)K;
}

// async global->LDS, 16B per lane (wave-uniform base + lane*16)
__device__ __forceinline__ void load16(const u16* g, u16* l) {
  __builtin_amdgcn_global_load_lds(
      (const __attribute__((address_space(1))) uint32_t*)(uintptr_t)g,
      (__attribute__((address_space(3))) uint32_t*)(uintptr_t)l,
      16, 0, 0);
}

// ---------------- GEMM: C[m,n] = scale[n] * sum_k A[m,k]*B[n,k] ----------------
// A: [M,K] bf16 signs, B: [N,K] bf16 signs (weight's natural layout = B^T GEMM)
// 256 threads = 4 waves in 2x2; each wave does 64x64 via 4x4 of 16x16x32 MFMA.
__global__ __launch_bounds__(256, 3) void gemm_bt_kernel(
    const u16* __restrict__ A, const u16* __restrict__ B,
    const float* __restrict__ scale, float* __restrict__ C,
    int M, int N, int K) {
  __shared__ __align__(16) u16 As[BM * BK];
  __shared__ __align__(16) u16 Bs[BN * BK];

  const int tid = threadIdx.x;
  const int lane = tid & 63;
  const int wave = tid >> 6;
  const int waveM = wave & 1;
  const int waveN = wave >> 1;

  const int rowA0 = blockIdx.y * BM;
  const int rowB0 = blockIdx.x * BN;

  // staging: per wave 2 insts for A (16 rows each, 64B/row) + 2 for B
  const u16* aG = A + (size_t)(rowA0 + wave * 32 + (lane >> 2)) * K + (lane & 3) * 8;
  const u16* bG = B + (size_t)(rowB0 + wave * 32 + (lane >> 2)) * K + (lane & 3) * 8;
  u16* aL = As + wave * 1024 + lane * 8;
  u16* bL = Bs + wave * 1024 + lane * 8;
  const size_t stride16 = (size_t)16 * K;

  // fragment read offsets: A[m=lane&15][k=(lane>>4)*8+j], same for B (n=lane&15)
  const int fRow = lane & 15;
  const int fK = (lane >> 4) * 8;
  const u16* aF = As + (waveM * 64 + fRow) * BK + fK;
  const u16* bF = Bs + (waveN * 64 + fRow) * BK + fK;

  f32x4 acc[4][4] = {};

  for (int k0 = 0; k0 < K; k0 += BK) {
    __syncthreads();  // previous iter's LDS reads done before overwrite
    load16(aG + k0, aL);
    load16(aG + k0 + stride16, aL + 512);
    load16(bG + k0, bL);
    load16(bG + k0 + stride16, bL + 512);
    __syncthreads();  // staging complete (compiler drains vmcnt before barrier)

    bf16x8 av[4], bv[4];
#pragma unroll
    for (int i = 0; i < 4; ++i) {
      av[i] = *(const bf16x8*)(aF + i * 16 * BK);
      bv[i] = *(const bf16x8*)(bF + i * 16 * BK);
    }
#pragma unroll
    for (int mi = 0; mi < 4; ++mi)
#pragma unroll
      for (int ni = 0; ni < 4; ++ni)
        acc[mi][ni] =
            __builtin_amdgcn_mfma_f32_16x16x32_bf16(av[mi], bv[ni], acc[mi][ni], 0, 0, 0);
  }

  // epilogue: C/D layout col=lane&15, row=(lane>>4)*4+r  (HW-verified mapping)
  const int cRow0 = rowA0 + waveM * 64 + ((lane >> 4) * 4);
  const int cCol0 = rowB0 + waveN * 64 + (lane & 15);
  float sc[4];
#pragma unroll
  for (int ni = 0; ni < 4; ++ni) sc[ni] = scale[cCol0 + ni * 16];
#pragma unroll
  for (int mi = 0; mi < 4; ++mi)
#pragma unroll
    for (int ni = 0; ni < 4; ++ni)
#pragma unroll
      for (int r = 0; r < 4; ++r)
        C[(size_t)(cRow0 + mi * 16 + r) * N + (cCol0 + ni * 16)] = acc[mi][ni][r] * sc[ni];
}

// ---------------- fallback (only if ws_size < 96 MiB): exact, slow ----------------
__global__ void fallback_gemm(const float* __restrict__ X, const float* __restrict__ W,
                              float* __restrict__ C, int M, int N, int K) {
  __shared__ float xs[16][65];
  __shared__ float ws[16][65];
  __shared__ float wabs[256];
  __shared__ float scl[16];
  const int tx = threadIdx.x, ty = threadIdx.y;
  const int t = ty * 16 + tx;
  float acc = 0.f, wa = 0.f;
  for (int k0 = 0; k0 < K; k0 += 64) {
    __syncthreads();
#pragma unroll
    for (int j = 0; j < 4; ++j) {
      int e = t * 4 + j;
      int r = e >> 6, c = e & 63;
      float xv = X[(size_t)(blockIdx.y * 16 + r) * K + k0 + c];
      xs[r][c] = xv > 0.f ? 1.f : (xv < 0.f ? -1.f : 0.f);
      float wv = W[(size_t)(blockIdx.x * 16 + r) * K + k0 + c];
      ws[r][c] = wv > 0.f ? 1.f : (wv < 0.f ? -1.f : 0.f);
      wa += fabsf(wv);
    }
    __syncthreads();
#pragma unroll 8
    for (int k = 0; k < 64; ++k) acc += xs[ty][k] * ws[tx][k];
  }
  wabs[t] = wa;
  __syncthreads();
  for (int s2 = 8; s2 > 0; s2 >>= 1) {
    if (tx < s2) wabs[t] += wabs[t + s2];
    __syncthreads();
  }
  if (tx == 0) scl[ty] = wabs[t] / (float)K;
  __syncthreads();
  C[(size_t)(blockIdx.y * 16 + ty) * N + (blockIdx.x * 16 + tx)] = acc * scl[tx];
}

extern "C" void kernel_launch(void* const* d_in, const int* in_sizes, int n_in,
                              void* d_out, int out_size, void* d_ws, size_t ws_size,
                              hipStream_t stream) {
  const float* x = (const float*)d_in[0];
  const float* w = (const float*)d_in[1];
  float* out = (float*)d_out;

  const int K = 4096;
  const int N = in_sizes[1] / K;  // 4096
  const int M = in_sizes[0] / K;  // 8192

  size_t need = (size_t)M * K * sizeof(u16) + (size_t)N * K * sizeof(u16) + (size_t)N * sizeof(float);
  if (ws_size >= need) {
    u16* Xq = (u16*)d_ws;
    u16* Wq = Xq + (size_t)M * K;
    float* scale = (float*)(Wq + (size_t)N * K);

    int n4 = (M * K) / 4;
    quant_x_kernel<<<(n4 + 255) / 256, 256, 0, stream>>>((const float4*)x, (ushort4*)Xq, n4);
    quant_w_kernel<<<N, 256, 0, stream>>>(w, Wq, scale, K);

    dim3 grid(N / BN, M / BM);
    gemm_bt_kernel<<<grid, 256, 0, stream>>>(Xq, Wq, scale, out, M, N, K);
  } else {
    dim3 grid(N / 16, M / 16);
    fallback_gemm<<<grid, dim3(16, 16), 0, stream>>>(x, w, out, M, N, K);
  }
}

// Round 2
// 402.542 us; speedup vs baseline: 1.3634x; 1.3634x over previous
//
#include <hip/hip_runtime.h>
#include <stdint.h>

typedef unsigned short u16;
typedef __attribute__((ext_vector_type(4))) int i32x4;

#define BM 128
#define BN 128
#define BKB 64  // K-depth per tile in bytes (64 i8 elements)

// i8 signs: +1 = 1, -1 = 0xFF, 0 = 0 (matches jnp.sign)
__device__ __forceinline__ uint32_t sign_i8(float v) {
  return v > 0.f ? 1u : (v < 0.f ? 0xFFu : 0u);
}

__device__ __forceinline__ uint32_t pack4(float a, float b, float c, float d) {
  return sign_i8(a) | (sign_i8(b) << 8) | (sign_i8(c) << 16) | (sign_i8(d) << 24);
}

// ---------------- quantize x: fp32 -> i8 sign, 16 elems/thread ----------------
__global__ void quant_x_kernel(const float4* __restrict__ x, int4* __restrict__ xq, int n16) {
  int i = blockIdx.x * 256 + threadIdx.x;
  if (i >= n16) return;
  float4 v0 = x[i * 4 + 0], v1 = x[i * 4 + 1], v2 = x[i * 4 + 2], v3 = x[i * 4 + 3];
  int4 s;
  s.x = (int)pack4(v0.x, v0.y, v0.z, v0.w);
  s.y = (int)pack4(v1.x, v1.y, v1.z, v1.w);
  s.z = (int)pack4(v2.x, v2.y, v2.z, v2.w);
  s.w = (int)pack4(v3.x, v3.y, v3.z, v3.w);
  xq[i] = s;
}

// ------------- quantize w: one block per row; i8 signs + mean(|w|) scale -------------
__global__ void quant_w_kernel(const float* __restrict__ w, uint8_t* __restrict__ wq,
                               float* __restrict__ scale, int K) {
  const int row = blockIdx.x;
  const int t = threadIdx.x;
  const float* wr = w + (size_t)row * K;
  uint8_t* wqr = wq + (size_t)row * K;
  float asum = 0.f;
  for (int p = 0; p < K; p += 1024) {  // 256 threads * float4 per pass
    int idx = p + t * 4;
    float4 v = *(const float4*)(wr + idx);
    uint32_t s = pack4(v.x, v.y, v.z, v.w);
    *(uint32_t*)(wqr + idx) = s;
    asum += fabsf(v.x) + fabsf(v.y) + fabsf(v.z) + fabsf(v.w);
  }
  __shared__ float red[256];
  red[t] = asum;
  __syncthreads();
  for (int s2 = 128; s2 > 0; s2 >>= 1) {
    if (t < s2) red[t] += red[t + s2];
    __syncthreads();
  }
  if (t == 0) scale[row] = red[0] / (float)K;
}

// async global->LDS, 16B per lane (wave-uniform base + lane*16)
__device__ __forceinline__ void load16(const uint8_t* g, uint8_t* l) {
  __builtin_amdgcn_global_load_lds(
      (const __attribute__((address_space(1))) uint32_t*)(uintptr_t)g,
      (__attribute__((address_space(3))) uint32_t*)(uintptr_t)l,
      16, 0, 0);
}

// ---------------- GEMM: C[m,n] = scale[n] * sum_k A[m,k]*B[n,k] ----------------
// A: [M,K] i8 signs, B: [N,K] i8 signs. mfma_i32_16x16x64_i8, i32 exact accumulate.
// 256 threads = 4 waves in 2x2; each wave does 64x64 via 4x4 of 16x16 tiles.
__global__ __launch_bounds__(256, 3) void gemm_bt_kernel(
    const uint8_t* __restrict__ A, const uint8_t* __restrict__ B,
    const float* __restrict__ scale, float* __restrict__ C,
    int M, int N, int K) {
  __shared__ __align__(16) uint8_t As[BM * BKB];  // 8 KB
  __shared__ __align__(16) uint8_t Bs[BN * BKB];  // 8 KB

  const int tid = threadIdx.x;
  const int lane = tid & 63;
  const int wave = tid >> 6;
  const int waveM = wave & 1;
  const int waveN = wave >> 1;

  const int rowA0 = blockIdx.y * BM;
  const int rowB0 = blockIdx.x * BN;

  // staging: per wave 2 insts for A (16 rows each, 64 B/row = 4 lanes) + 2 for B
  const uint8_t* aG = A + (size_t)(rowA0 + wave * 32 + (lane >> 2)) * K + (lane & 3) * 16;
  const uint8_t* bG = B + (size_t)(rowB0 + wave * 32 + (lane >> 2)) * K + (lane & 3) * 16;
  uint8_t* aL = As + wave * 2048 + lane * 16;
  uint8_t* bL = Bs + wave * 2048 + lane * 16;
  const size_t stride16 = (size_t)16 * K;

  // fragment: A[m=lane&15][k=(lane>>4)*16 + j], j=0..15 (16 contiguous i8 = 16 B)
  const int fRow = lane & 15;
  const int fKB = (lane >> 4) * 16;  // byte offset in row
  const uint8_t* aF = As + (waveM * 64 + fRow) * BKB + fKB;
  const uint8_t* bF = Bs + (waveN * 64 + fRow) * BKB + fKB;

  i32x4 acc[4][4] = {};

  for (int k0 = 0; k0 < K; k0 += BKB) {
    __syncthreads();  // previous iter's LDS reads done before overwrite
    load16(aG + k0, aL);
    load16(aG + k0 + stride16, aL + 1024);
    load16(bG + k0, bL);
    load16(bG + k0 + stride16, bL + 1024);
    __syncthreads();  // staging complete (vmcnt drained before barrier)

    i32x4 av[4], bv[4];
#pragma unroll
    for (int i = 0; i < 4; ++i) {
      av[i] = *(const i32x4*)(aF + i * 16 * BKB);
      bv[i] = *(const i32x4*)(bF + i * 16 * BKB);
    }
#pragma unroll
    for (int mi = 0; mi < 4; ++mi)
#pragma unroll
      for (int ni = 0; ni < 4; ++ni)
        acc[mi][ni] =
            __builtin_amdgcn_mfma_i32_16x16x64_i8(av[mi], bv[ni], acc[mi][ni], 0, 0, 0);
  }

  // epilogue: C/D layout col=lane&15, row=(lane>>4)*4+r (dtype-independent, HW-verified)
  const int cRow0 = rowA0 + waveM * 64 + ((lane >> 4) * 4);
  const int cCol0 = rowB0 + waveN * 64 + (lane & 15);
  float sc[4];
#pragma unroll
  for (int ni = 0; ni < 4; ++ni) sc[ni] = scale[cCol0 + ni * 16];
#pragma unroll
  for (int mi = 0; mi < 4; ++mi)
#pragma unroll
    for (int ni = 0; ni < 4; ++ni)
#pragma unroll
      for (int r = 0; r < 4; ++r)
        C[(size_t)(cRow0 + mi * 16 + r) * N + (cCol0 + ni * 16)] =
            (float)acc[mi][ni][r] * sc[ni];
}

// ---------------- fallback (only if ws too small): exact, slow ----------------
__global__ void fallback_gemm(const float* __restrict__ X, const float* __restrict__ W,
                              float* __restrict__ C, int M, int N, int K) {
  __shared__ float xs[16][65];
  __shared__ float ws[16][65];
  __shared__ float wabs[256];
  __shared__ float scl[16];
  const int tx = threadIdx.x, ty = threadIdx.y;
  const int t = ty * 16 + tx;
  float acc = 0.f, wa = 0.f;
  for (int k0 = 0; k0 < K; k0 += 64) {
    __syncthreads();
#pragma unroll
    for (int j = 0; j < 4; ++j) {
      int e = t * 4 + j;
      int r = e >> 6, c = e & 63;
      float xv = X[(size_t)(blockIdx.y * 16 + r) * K + k0 + c];
      xs[r][c] = xv > 0.f ? 1.f : (xv < 0.f ? -1.f : 0.f);
      float wv = W[(size_t)(blockIdx.x * 16 + r) * K + k0 + c];
      ws[r][c] = wv > 0.f ? 1.f : (wv < 0.f ? -1.f : 0.f);
      wa += fabsf(wv);
    }
    __syncthreads();
#pragma unroll 8
    for (int k = 0; k < 64; ++k) acc += xs[ty][k] * ws[tx][k];
  }
  wabs[t] = wa;
  __syncthreads();
  for (int s2 = 8; s2 > 0; s2 >>= 1) {
    if (tx < s2) wabs[t] += wabs[t + s2];
    __syncthreads();
  }
  if (tx == 0) scl[ty] = wabs[t] / (float)K;
  __syncthreads();
  C[(size_t)(blockIdx.y * 16 + ty) * N + (blockIdx.x * 16 + tx)] = acc * scl[tx];
}

extern "C" void kernel_launch(void* const* d_in, const int* in_sizes, int n_in,
                              void* d_out, int out_size, void* d_ws, size_t ws_size,
                              hipStream_t stream) {
  const float* x = (const float*)d_in[0];
  const float* w = (const float*)d_in[1];
  float* out = (float*)d_out;

  const int K = 4096;
  const int N = in_sizes[1] / K;  // 4096
  const int M = in_sizes[0] / K;  // 8192

  size_t need = (size_t)M * K + (size_t)N * K + (size_t)N * sizeof(float);
  if (ws_size >= need) {
    uint8_t* Xq = (uint8_t*)d_ws;
    uint8_t* Wq = Xq + (size_t)M * K;
    float* scale = (float*)(Wq + (size_t)N * K);

    int n16 = (M * K) / 16;
    quant_x_kernel<<<(n16 + 255) / 256, 256, 0, stream>>>((const float4*)x, (int4*)Xq, n16);
    quant_w_kernel<<<N, 256, 0, stream>>>(w, Wq, scale, K);

    dim3 grid(N / BN, M / BM);
    gemm_bt_kernel<<<grid, 256, 0, stream>>>(Xq, Wq, scale, out, M, N, K);
  } else {
    dim3 grid(N / 16, M / 16);
    fallback_gemm<<<grid, dim3(16, 16), 0, stream>>>(x, w, out, M, N, K);
  }
}

// Round 3
// 342.891 us; speedup vs baseline: 1.6006x; 1.1740x over previous
//
#include <hip/hip_runtime.h>
#include <stdint.h>

typedef __attribute__((ext_vector_type(4))) int i32x4;
typedef __attribute__((ext_vector_type(8))) int i32x8;
typedef __attribute__((ext_vector_type(16))) float f32x16;

#define BM 128
#define BN 128
// K per LDS tile = 128 fp4 elements = 64 bytes per row

// fp4 e2m1 signs: +1 = 0x2, -1 = 0xA, 0 = 0x0 (matches jnp.sign exactly)
__device__ __forceinline__ uint32_t nib4(float v) {
  return v > 0.f ? 0x2u : (v < 0.f ? 0xAu : 0u);
}

// 8 fp32 -> 8 nibbles in one u32 (element j -> nibble j, low nibble first)
__device__ __forceinline__ uint32_t pack8(float4 a, float4 b) {
  return nib4(a.x) | (nib4(a.y) << 4) | (nib4(a.z) << 8) | (nib4(a.w) << 12) |
         (nib4(b.x) << 16) | (nib4(b.y) << 20) | (nib4(b.z) << 24) | (nib4(b.w) << 28);
}

// ---------------- quantize x: fp32 -> fp4 signs, 32 elems/thread ----------------
__global__ void quant_x_kernel(const float4* __restrict__ x, int4* __restrict__ xq, int n) {
  int i = blockIdx.x * 256 + threadIdx.x;
  if (i >= n) return;
  float4 v0 = x[i * 8 + 0], v1 = x[i * 8 + 1], v2 = x[i * 8 + 2], v3 = x[i * 8 + 3];
  float4 v4 = x[i * 8 + 4], v5 = x[i * 8 + 5], v6 = x[i * 8 + 6], v7 = x[i * 8 + 7];
  int4 s;
  s.x = (int)pack8(v0, v1);
  s.y = (int)pack8(v2, v3);
  s.z = (int)pack8(v4, v5);
  s.w = (int)pack8(v6, v7);
  xq[i] = s;
}

// ---- quantize w: one block per row; fp4 signs + mean(|w|) scale ----
__global__ void quant_w_kernel(const float* __restrict__ w, uint8_t* __restrict__ wq,
                               float* __restrict__ scale, int K) {
  const int row = blockIdx.x;
  const int t = threadIdx.x;
  const float4* wr4 = (const float4*)(w + (size_t)row * K);
  // thread t handles elements [t*16, t*16+16) -> 8 bytes
  float4 v0 = wr4[t * 4 + 0], v1 = wr4[t * 4 + 1], v2 = wr4[t * 4 + 2], v3 = wr4[t * 4 + 3];
  uint2 o;
  o.x = pack8(v0, v1);
  o.y = pack8(v2, v3);
  ((uint2*)(wq + (size_t)row * (K / 2)))[t] = o;
  float asum = fabsf(v0.x) + fabsf(v0.y) + fabsf(v0.z) + fabsf(v0.w) +
               fabsf(v1.x) + fabsf(v1.y) + fabsf(v1.z) + fabsf(v1.w) +
               fabsf(v2.x) + fabsf(v2.y) + fabsf(v2.z) + fabsf(v2.w) +
               fabsf(v3.x) + fabsf(v3.y) + fabsf(v3.z) + fabsf(v3.w);
  __shared__ float red[256];
  red[t] = asum;
  __syncthreads();
  for (int s2 = 128; s2 > 0; s2 >>= 1) {
    if (t < s2) red[t] += red[t + s2];
    __syncthreads();
  }
  if (t == 0) scale[row] = red[0] / (float)K;
}

// async global->LDS, 16B per lane (wave-uniform base + lane*16)
__device__ __forceinline__ void load16(const uint8_t* g, uint8_t* l) {
  __builtin_amdgcn_global_load_lds(
      (const __attribute__((address_space(1))) uint32_t*)(uintptr_t)g,
      (__attribute__((address_space(3))) uint32_t*)(uintptr_t)l,
      16, 0, 0);
}

// ---------------- GEMM: C[m,n] = scale[n] * sum_k A[m,k]*B[n,k] ----------------
// A: [M,K/2] fp4-pair bytes, B: [N,K/2]. mfma_scale 32x32x64 f8f6f4, FMT=4 (fp4),
// scales pinned to 1.0 (e8m0 0x7F). fp32 accumulate is exact for +-1 sums.
// 256 threads = 4 waves in 2x2; each wave does 64x64 via 2x2 of 32x32 tiles.
__global__ __launch_bounds__(256, 3) void gemm_bt_kernel(
    const uint8_t* __restrict__ A, const uint8_t* __restrict__ B,
    const float* __restrict__ scale, float* __restrict__ C,
    int M, int N, int K) {
  __shared__ __align__(16) uint8_t As[BM * 64];  // 8 KB: 128 rows x 64 B (=128 fp4)
  __shared__ __align__(16) uint8_t Bs[BN * 64];  // 8 KB

  const int tid = threadIdx.x;
  const int lane = tid & 63;
  const int wave = tid >> 6;
  const int waveM = wave & 1;
  const int waveN = wave >> 1;

  const int rowA0 = blockIdx.y * BM;
  const int rowB0 = blockIdx.x * BN;

  const int KB = K / 2;  // row stride in bytes

  // staging: per wave 2 insts for A (16 rows each, 64 B/row = 4 lanes/row) + 2 for B
  const uint8_t* aG = A + (size_t)(rowA0 + wave * 32 + (lane >> 2)) * KB + (lane & 3) * 16;
  const uint8_t* bG = B + (size_t)(rowB0 + wave * 32 + (lane >> 2)) * KB + (lane & 3) * 16;
  uint8_t* aL = As + wave * 2048 + lane * 16;
  uint8_t* bL = Bs + wave * 2048 + lane * 16;
  const size_t strideG16 = (size_t)16 * KB;

  // fragment: lane holds row m=lane&31, K-group (lane>>5): 32 fp4 = 16 B
  const uint8_t* aF = As + (size_t)(waveM * 64 + (lane & 31)) * 64 + (lane >> 5) * 16;
  const uint8_t* bF = Bs + (size_t)(waveN * 64 + (lane & 31)) * 64 + (lane >> 5) * 16;

  f32x16 acc[2][2] = {};
  // persistent v8i32 operands; high 4 regs stay zero (fp4 uses low 4 only)
  i32x8 aop[2] = {}, bop[2] = {};

  for (int kb = 0; kb < KB; kb += 64) {
    __syncthreads();  // previous iter's LDS reads done before overwrite
    load16(aG + kb, aL);
    load16(aG + kb + strideG16, aL + 1024);
    load16(bG + kb, bL);
    load16(bG + kb + strideG16, bL + 1024);
    __syncthreads();  // staging complete (vmcnt drained before barrier)

#pragma unroll
    for (int s = 0; s < 2; ++s) {  // two K=64 MFMA steps per 64-B row tile
#pragma unroll
      for (int mi = 0; mi < 2; ++mi) {
        i32x4 t = *(const i32x4*)(aF + mi * 32 * 64 + s * 32);
        aop[mi].s0 = t.x; aop[mi].s1 = t.y; aop[mi].s2 = t.z; aop[mi].s3 = t.w;
      }
#pragma unroll
      for (int ni = 0; ni < 2; ++ni) {
        i32x4 t = *(const i32x4*)(bF + ni * 32 * 64 + s * 32);
        bop[ni].s0 = t.x; bop[ni].s1 = t.y; bop[ni].s2 = t.z; bop[ni].s3 = t.w;
      }
#pragma unroll
      for (int mi = 0; mi < 2; ++mi)
#pragma unroll
        for (int ni = 0; ni < 2; ++ni)
          acc[mi][ni] = __builtin_amdgcn_mfma_scale_f32_32x32x64_f8f6f4(
              aop[mi], bop[ni], acc[mi][ni],
              /*cbsz=fp4*/ 4, /*blgp=fp4*/ 4,
              /*opsel_a*/ 0, 0x7f7f7f7f, /*opsel_b*/ 0, 0x7f7f7f7f);
    }
  }

  // epilogue: 32x32 C/D layout col=lane&31, row=(reg&3)+8*(reg>>2)+4*(lane>>5)
  // (HW-verified, dtype-independent)
  const int cCol = rowB0 + waveN * 64 + (lane & 31);
  const int cRowBase = rowA0 + waveM * 64 + 4 * (lane >> 5);
  float sc[2];
#pragma unroll
  for (int ni = 0; ni < 2; ++ni) sc[ni] = scale[cCol + ni * 32];
#pragma unroll
  for (int mi = 0; mi < 2; ++mi)
#pragma unroll
    for (int ni = 0; ni < 2; ++ni)
#pragma unroll
      for (int r = 0; r < 16; ++r) {
        int row = cRowBase + mi * 32 + (r & 3) + 8 * (r >> 2);
        C[(size_t)row * N + cCol + ni * 32] = acc[mi][ni][r] * sc[ni];
      }
}

// ---------------- fallback (only if ws too small): exact, slow ----------------
__global__ void fallback_gemm(const float* __restrict__ X, const float* __restrict__ W,
                              float* __restrict__ C, int M, int N, int K) {
  __shared__ float xs[16][65];
  __shared__ float ws[16][65];
  __shared__ float wabs[256];
  __shared__ float scl[16];
  const int tx = threadIdx.x, ty = threadIdx.y;
  const int t = ty * 16 + tx;
  float acc = 0.f, wa = 0.f;
  for (int k0 = 0; k0 < K; k0 += 64) {
    __syncthreads();
#pragma unroll
    for (int j = 0; j < 4; ++j) {
      int e = t * 4 + j;
      int r = e >> 6, c = e & 63;
      float xv = X[(size_t)(blockIdx.y * 16 + r) * K + k0 + c];
      xs[r][c] = xv > 0.f ? 1.f : (xv < 0.f ? -1.f : 0.f);
      float wv = W[(size_t)(blockIdx.x * 16 + r) * K + k0 + c];
      ws[r][c] = wv > 0.f ? 1.f : (wv < 0.f ? -1.f : 0.f);
      wa += fabsf(wv);
    }
    __syncthreads();
#pragma unroll 8
    for (int k = 0; k < 64; ++k) acc += xs[ty][k] * ws[tx][k];
  }
  wabs[t] = wa;
  __syncthreads();
  for (int s2 = 8; s2 > 0; s2 >>= 1) {
    if (tx < s2) wabs[t] += wabs[t + s2];
    __syncthreads();
  }
  if (tx == 0) scl[ty] = wabs[t] / (float)K;
  __syncthreads();
  C[(size_t)(blockIdx.y * 16 + ty) * N + (blockIdx.x * 16 + tx)] = acc * scl[tx];
}

extern "C" void kernel_launch(void* const* d_in, const int* in_sizes, int n_in,
                              void* d_out, int out_size, void* d_ws, size_t ws_size,
                              hipStream_t stream) {
  const float* x = (const float*)d_in[0];
  const float* w = (const float*)d_in[1];
  float* out = (float*)d_out;

  const int K = 4096;
  const int N = in_sizes[1] / K;  // 4096
  const int M = in_sizes[0] / K;  // 8192

  size_t need = (size_t)M * (K / 2) + (size_t)N * (K / 2) + (size_t)N * sizeof(float);
  if (ws_size >= need) {
    uint8_t* Xq = (uint8_t*)d_ws;
    uint8_t* Wq = Xq + (size_t)M * (K / 2);
    float* scale = (float*)(Wq + (size_t)N * (K / 2));

    int n32 = (M * K) / 32;
    quant_x_kernel<<<(n32 + 255) / 256, 256, 0, stream>>>((const float4*)x, (int4*)Xq, n32);
    quant_w_kernel<<<N, 256, 0, stream>>>(w, Wq, scale, K);

    dim3 grid(N / BN, M / BM);
    gemm_bt_kernel<<<grid, 256, 0, stream>>>(Xq, Wq, scale, out, M, N, K);
  } else {
    dim3 grid(N / 16, M / 16);
    fallback_gemm<<<grid, dim3(16, 16), 0, stream>>>(x, w, out, M, N, K);
  }
}